// Round 5
// baseline (1201.055 us; speedup 1.0000x reference)
//
#include <hip/hip_runtime.h>

typedef unsigned short u16;
typedef unsigned int u32;
typedef unsigned long long u64;
typedef int   v4i  __attribute__((ext_vector_type(4)));
typedef short v8s  __attribute__((ext_vector_type(8)));
typedef float v2f  __attribute__((ext_vector_type(2)));
typedef float v16f __attribute__((ext_vector_type(16)));

#define B_ 256
#define T_ 120
#define E_ 256
#define H_ 1024
#define K_ 1280
#define LDH 1032    // 1024 + 8 pad (u16); halves [0,512),[512,1024) stay contiguous
#define LDX 264     // 256 + 8 pad

// ---- ws layout (bytes) ----
#define WS_WF   0                    // 10,485,760  (W fragments, bf16)
#define WS_X    10485760             // 15,728,640  (X (T,B,E) bf16)
#define WS_HS   26214400             // 62,914,560  (hs (T,B,H) bf16)
#define WS_BAR  89128960             // 7,680 (8 mgroups x 120 steps x 2 halves)

__device__ __forceinline__ u16 f2bf(float f) {
    union { float f; u32 u; } v; v.f = f;
    u32 r = v.u + 0x7fffu + ((v.u >> 16) & 1u);   // RNE
    return (u16)(r >> 16);
}
__device__ __forceinline__ float bf2f(u16 u) {
    union { u32 u; float f; } v; v.u = ((u32)u) << 16; return v.f;
}
__device__ __forceinline__ float fsig(float x) {
    float t = __builtin_amdgcn_exp2f(-1.44269504f * x);
    return __builtin_amdgcn_rcpf(1.0f + t);
}
__device__ __forceinline__ float ftanh_(float x) {
    float xc = fminf(8.0f, fmaxf(-8.0f, x));
    float t = __builtin_amdgcn_exp2f(2.88539008f * xc);
    return (t - 1.0f) * __builtin_amdgcn_rcpf(t + 1.0f);
}
__device__ __forceinline__ void gl_lds16(const void* g, void* l) {
    __builtin_amdgcn_global_load_lds(
        (const __attribute__((address_space(1))) void*)g,
        (__attribute__((address_space(3))) void*)l, 16, 0, 0);
}

// ---------------- P1: W (1280,4096) f32 -> bf16 32x32x16 B-fragments ----------------
// cid = nc*8 + np*4 + kq (0..255). Wave (np,kq) owns gates {2np,2np+1}, K cols
// s = 4f+kq (f 0..19). Chunk layout: [f][n][lane][j8]; elem (l,j):
//   W[(4f+kq)*16 + (l>>5)*8 + j][(2np+n)*1024 + nc*32 + (l&31)]
// Block = (cid, fo 0..4) covers f = fo*4..fo*4+3, both n.
__global__ void prep_w(const float* __restrict__ W, u16* __restrict__ Wf) {
    __shared__ u16 tile[64 * 72];         // [n*32+col][fl*16+krow + pad]
    int bid = blockIdx.x;
    int cid = bid / 5, fo = bid % 5;
    int kq  = cid & 3, np = (cid >> 2) & 1, nc = cid >> 3;
    int tid = threadIdx.x;
    int cc = tid & 31, n = (tid >> 5) & 1, r = tid >> 6;   // r 0..3

    int col = (np * 2 + n) * 1024 + nc * 32 + cc;
#pragma unroll
    for (int fl = 0; fl < 4; ++fl) {
        int k0 = (4 * (fo * 4 + fl) + kq) * 16;
#pragma unroll
        for (int rr = 0; rr < 4; ++rr) {
            int krow = rr * 4 + r;
            float v = W[(size_t)(k0 + krow) * 4096 + col];
            tile[(n * 32 + cc) * 72 + fl * 16 + krow] = f2bf(v);
        }
    }
    __syncthreads();

    int lane = tid & 63, wvv = tid >> 6;
#pragma unroll
    for (int pass = 0; pass < 2; ++pass) {
        int slot = wvv + pass * 4;        // (fl = slot>>1, n = slot&1)
        int fl = slot >> 1, nn = slot & 1;
        v4i o = *(const v4i*)&tile[(nn * 32 + (lane & 31)) * 72 + fl * 16 + ((lane >> 5) << 3)];
        *(v4i*)(Wf + (size_t)cid * 20480 + (((fo * 4 + fl) * 2 + nn) << 9) + lane * 8) = o;
    }
}

// ---------------- P2: embedding gather -> X (T,B,E) bf16 ----------------
__global__ void prep_x(const int* __restrict__ tokens, const float* __restrict__ emb,
                       u16* __restrict__ X) {
    int v   = blockIdx.x * 256 + threadIdx.x;     // < 983040
    int e8  = v & 31;
    int row = v >> 5;                             // t*256 + b
    int t = row >> 8, b = row & 255;
    int tok = tokens[b * T_ + t];
    const float* src = emb + (size_t)tok * E_ + e8 * 8;
    u16 o[8];
#pragma unroll
    for (int j = 0; j < 8; ++j) o[j] = f2bf(src[j]);
    *(v4i*)(X + (size_t)row * E_ + e8 * 8) = *(v4i*)o;
}

// ---------------- main persistent LSTM kernel ----------------
// 256 blocks x 512 threads. Block (mchunk=bid&7, nc=bid>>3). Wave (np=wv>>2,
// kq=wv&3): gates {2np,2np+1} x K-quarter -> 2 MFMAs per A-frag read (A-LDS
// traffic halved vs per-gate waves). Per-wave flag polling + split col-half
// flags; chunked vmcnt-gated h staging via global_load_lds.
__global__ __launch_bounds__(512, 2) void lstm_main(
    const u16* __restrict__ Wf, const u16* __restrict__ X,
    const float* __restrict__ b_lstm, u16* __restrict__ hs,
    u32* __restrict__ bar) {

    __shared__ u16  hbuf[32 * LDH];           // 66,048 B
    __shared__ u16  xbuf[32 * LDX];           // 16,896 B
    __shared__ float gates[4 * 4 * 32 * 34];  // 69,632 B  [kq][gate][row][34]
    __shared__ float bias[128];               // 153,088 total

    const int tid   = threadIdx.x;
    const int lane  = tid & 63;
    const int wv    = tid >> 6;
    const int np    = wv >> 2;
    const int kq    = wv & 3;
    const int bid   = blockIdx.x;
    const int mchunk = bid & 7;
    const int nc    = bid >> 3;
    const int m0    = mchunk << 5;
    const int hl    = nc >> 4;                // col-half flag this block feeds

    if (tid < 128) bias[tid] = b_lstm[(tid >> 5) * H_ + (nc << 5) + (tid & 31)];

    // ---- resident W fragments: [f 0..19][n 0..1], pinned ----
    v8s Wr[20][2];
    {
        const v4i* wsrc = (const v4i*)(Wf + (size_t)(nc * 8 + np * 4 + kq) * 20480);
#pragma unroll
        for (int f = 0; f < 20; ++f)
#pragma unroll
            for (int n = 0; n < 2; ++n)
                Wr[f][n] = __builtin_bit_cast(v8s, wsrc[(f * 2 + n) * 64 + lane]);
    }
#pragma unroll
    for (int f = 0; f < 20; ++f) {
        asm volatile("" : "+v"(Wr[f][0]));
        asm volatile("" : "+v"(Wr[f][1]));
    }

    // ---- stage X_0 ----
    {
        const v4i* xs = (const v4i*)(X + (size_t)m0 * E_);
#pragma unroll
        for (int i = 0; i < 2; ++i) {
            int idx = tid + i * 512;
            int r = idx >> 5, c8 = idx & 31;
            *(v4i*)&xbuf[r * LDX + c8 * 8] = xs[r * 32 + c8];
        }
    }
    __syncthreads();

    const u16* Ax = &xbuf[(lane & 31) * LDX + ((lane >> 5) << 3)];
    const u16* Ah = &hbuf[(lane & 31) * LDH + ((lane >> 5) << 3)];

    float cst[2] = {0.f, 0.f};
    const int cm  = tid >> 4;
    const int cn2 = (tid & 15) << 1;
    u32* hs32 = (u32*)hs;

    for (int t = 0; t < T_; ++t) {
        v16f acc0 = {0,0,0,0,0,0,0,0,0,0,0,0,0,0,0,0};
        v16f acc1 = {0,0,0,0,0,0,0,0,0,0,0,0,0,0,0,0};

        if (t > 0) {
            const u32* flg = &bar[((size_t)mchunk * T_ + (t - 1)) * 2];
            const u16* srcb = hs + ((size_t)(t - 1) * B_ + m0) * H_;
            const int r0 = wv << 2;
            // ---- poll low half (per-wave, no block barrier), issue low loads ----
            while (__hip_atomic_load(&flg[0], __ATOMIC_RELAXED, __HIP_MEMORY_SCOPE_AGENT) < 16u)
                __builtin_amdgcn_s_sleep(1);
#pragma unroll
            for (int i = 0; i < 4; ++i)
                gl_lds16(srcb + (size_t)(r0 + i) * H_ + lane * 8,
                         &hbuf[(r0 + i) * LDH]);
            // ---- poll high half, issue high loads ----
            while (__hip_atomic_load(&flg[1], __ATOMIC_RELAXED, __HIP_MEMORY_SCOPE_AGENT) < 16u)
                __builtin_amdgcn_s_sleep(1);
#pragma unroll
            for (int i = 0; i < 4; ++i)
                gl_lds16(srcb + (size_t)(r0 + i) * H_ + 512 + lane * 8,
                         &hbuf[(r0 + i) * LDH + 512]);
            // ---- x-part MFMA (f 0..3) while h loads fly ----
#pragma unroll
            for (int f = 0; f < 4; ++f) {
                v8s a = *(const v8s*)(Ax + (4 * f + kq) * 16);
                acc0 = __builtin_amdgcn_mfma_f32_32x32x16_bf16(a, Wr[f][0], acc0, 0, 0, 0);
                acc1 = __builtin_amdgcn_mfma_f32_32x32x16_bf16(a, Wr[f][1], acc1, 0, 0, 0);
            }
            // ---- chunk A: h cols [0,512) (f 4..11) ----
            asm volatile("s_waitcnt vmcnt(4)\n\ts_barrier" ::: "memory");
#pragma unroll
            for (int f = 4; f < 12; ++f) {
                v8s a = *(const v8s*)(Ah + (4 * f + kq) * 16 - 256);
                acc0 = __builtin_amdgcn_mfma_f32_32x32x16_bf16(a, Wr[f][0], acc0, 0, 0, 0);
                acc1 = __builtin_amdgcn_mfma_f32_32x32x16_bf16(a, Wr[f][1], acc1, 0, 0, 0);
            }
            // ---- chunk B: h cols [512,1024) (f 12..19) ----
            asm volatile("s_waitcnt vmcnt(0)\n\ts_barrier" ::: "memory");
#pragma unroll
            for (int f = 12; f < 20; ++f) {
                v8s a = *(const v8s*)(Ah + (4 * f + kq) * 16 - 256);
                acc0 = __builtin_amdgcn_mfma_f32_32x32x16_bf16(a, Wr[f][0], acc0, 0, 0, 0);
                acc1 = __builtin_amdgcn_mfma_f32_32x32x16_bf16(a, Wr[f][1], acc1, 0, 0, 0);
            }
        } else {
            // t = 0: h_{-1} = 0, x-part only
#pragma unroll
            for (int f = 0; f < 4; ++f) {
                v8s a = *(const v8s*)(Ax + (4 * f + kq) * 16);
                acc0 = __builtin_amdgcn_mfma_f32_32x32x16_bf16(a, Wr[f][0], acc0, 0, 0, 0);
                acc1 = __builtin_amdgcn_mfma_f32_32x32x16_bf16(a, Wr[f][1], acc1, 0, 0, 0);
            }
        }

        // ---- partials -> LDS: C/D col=lane&31, row=(reg&3)+8*(reg>>2)+4*(lane>>5) ----
        {
            int col = lane & 31, rq = (lane >> 5) << 2;
            float* g0 = &gates[(kq * 4 + np * 2 + 0) * 1088];
            float* g1 = &gates[(kq * 4 + np * 2 + 1) * 1088];
#pragma unroll
            for (int reg = 0; reg < 16; ++reg) {
                int row = (reg & 3) + ((reg >> 2) << 3) + rq;
                g0[row * 34 + col] = acc0[reg];
                g1[row * 34 + col] = acc1[reg];
            }
        }
        __syncthreads();                      // (1) gates ready; hbuf/xbuf reads done

        // ---- prefetch X_{t+1} (overlaps cell transcendentals) ----
        if (t + 1 < T_) {
            const v4i* xs = (const v4i*)(X + ((size_t)(t + 1) * B_ + m0) * E_);
#pragma unroll
            for (int i = 0; i < 2; ++i) {
                int idx = tid + i * 512;
                int r = idx >> 5, c8 = idx & 31;
                *(v4i*)&xbuf[r * LDX + c8 * 8] = xs[r * 32 + c8];
            }
        }

        // ---- cell math: sum 4 K-partials, bias, activations ----
        u32 hpack = 0;
        {
            v2f zz[4];
#pragma unroll
            for (int gg = 0; gg < 4; ++gg) {
                v2f s0 = *(const v2f*)&gates[(0 * 4 + gg) * 1088 + cm * 34 + cn2];
                v2f s1 = *(const v2f*)&gates[(1 * 4 + gg) * 1088 + cm * 34 + cn2];
                v2f s2 = *(const v2f*)&gates[(2 * 4 + gg) * 1088 + cm * 34 + cn2];
                v2f s3 = *(const v2f*)&gates[(3 * 4 + gg) * 1088 + cm * 34 + cn2];
                zz[gg].x = (s0.x + s1.x) + (s2.x + s3.x);
                zz[gg].y = (s0.y + s1.y) + (s2.y + s3.y);
            }
#pragma unroll
            for (int q = 0; q < 2; ++q) {
                int n = cn2 + q;
                float ip = zz[0][q] + bias[n];
                float jp = zz[1][q] + bias[32 + n];
                float fp = zz[2][q] + bias[64 + n] + 1.0f;
                float op = zz[3][q] + bias[96 + n];
                float cc = fsig(fp) * cst[q] + fsig(ip) * ftanh_(jp);
                cst[q] = cc;
                hpack |= ((u32)f2bf(fsig(op) * ftanh_(cc))) << (16 * q);
            }
        }
        __hip_atomic_store(&hs32[((size_t)t * B_ + m0 + cm) * 512 + (nc << 4) + (tid & 15)],
                           hpack, __ATOMIC_RELAXED, __HIP_MEMORY_SCOPE_AGENT);

        if (t + 1 < T_) {
            // ---- release: drain own stores, block rendezvous (also covers xbuf), flag ----
            asm volatile("s_waitcnt vmcnt(0)" ::: "memory");
            __syncthreads();                  // (2)
            if (tid == 0)
                __hip_atomic_fetch_add(&bar[((size_t)mchunk * T_ + t) * 2 + hl], 1u,
                                       __ATOMIC_RELAXED, __HIP_MEMORY_SCOPE_AGENT);
        }
    }
}

// ---------------- P3: preds = hs @ U + b2 (64 rows/block; U staged once) ----------------
__global__ void proj_kernel(const u16* __restrict__ hs, const float* __restrict__ U,
                            const float* __restrict__ b2, float* __restrict__ out) {
    __shared__ float Ul[H_ * 5];
    int tid = threadIdx.x;
    for (int i = tid; i < H_ * 5; i += 256) Ul[i] = U[i];
    __syncthreads();
    int wv = tid >> 6, lane = tid & 63;
#pragma unroll 1
    for (int i = 0; i < 16; ++i) {
        int row = blockIdx.x * 64 + wv * 16 + i;   // t*256 + b, < 30720
        int t = row >> 8, b = row & 255;
        const v4i* hp = (const v4i*)(hs + (size_t)row * H_);
        float p[5] = {0.f, 0.f, 0.f, 0.f, 0.f};
#pragma unroll
        for (int half = 0; half < 2; ++half) {
            v4i hv = hp[lane * 2 + half];
            u16 us[8];
            *(v4i*)us = hv;
#pragma unroll
            for (int j = 0; j < 8; ++j) {
                float hf = bf2f(us[j]);
                int k = lane * 16 + half * 8 + j;
#pragma unroll
                for (int c = 0; c < 5; ++c) p[c] += hf * Ul[k * 5 + c];
            }
        }
#pragma unroll
        for (int c = 0; c < 5; ++c)
            for (int off = 32; off > 0; off >>= 1)
                p[c] += __shfl_down(p[c], off, 64);
        if (lane == 0) {
#pragma unroll
            for (int c = 0; c < 5; ++c)
                out[((size_t)b * T_ + t) * 5 + c] = p[c] + b2[c];
        }
    }
}

extern "C" void kernel_launch(void* const* d_in, const int* in_sizes, int n_in,
                              void* d_out, int out_size, void* d_ws, size_t ws_size,
                              hipStream_t stream) {
    const int*   tokens = (const int*)d_in[0];
    const float* emb    = (const float*)d_in[1];
    const float* W      = (const float*)d_in[2];
    const float* b_l    = (const float*)d_in[3];
    const float* U      = (const float*)d_in[4];
    const float* b2     = (const float*)d_in[5];
    float* out = (float*)d_out;

    char* ws = (char*)d_ws;
    u16* Wf  = (u16*)(ws + WS_WF);
    u16* X   = (u16*)(ws + WS_X);
    u16* hs  = (u16*)(ws + WS_HS);
    u32* bar = (u32*)(ws + WS_BAR);

    hipMemsetAsync(bar, 0, 8 * T_ * 2 * sizeof(u32), stream);
    prep_w<<<1280, 256, 0, stream>>>(W, Wf);
    prep_x<<<3840, 256, 0, stream>>>(tokens, emb, X);
    lstm_main<<<256, 512, 0, stream>>>(Wf, X, b_l, hs, bar);
    proj_kernel<<<480, 256, 0, stream>>>(hs, U, b2, out);
}

// Round 6
// 654.815 us; speedup vs baseline: 1.8342x; 1.8342x over previous
//
#include <hip/hip_runtime.h>

typedef unsigned short u16;
typedef unsigned int u32;
typedef unsigned long long u64;
typedef int   v4i  __attribute__((ext_vector_type(4)));
typedef short v8s  __attribute__((ext_vector_type(8)));
typedef float v2f  __attribute__((ext_vector_type(2)));
typedef float v16f __attribute__((ext_vector_type(16)));

#define B_ 256
#define T_ 120
#define E_ 256
#define H_ 1024
#define K_ 1280
#define LDH 1032    // 1024 + 8 pad (u16); halves [0,512),[512,1024) contiguous
#define LDX 264     // 256 + 8 pad

// ---- ws layout (bytes) ----
#define WS_WF   0                    // 10,485,760  (W fragments, bf16)
#define WS_X    10485760             // 15,728,640  (X (T,B,E) bf16)
#define WS_HS   26214400             // 62,914,560  (hs (T,B,H) bf16)
#define WS_BAR  89128960             // 61,440 (8 mgroups x 120 steps, 64B-padded flags)

__device__ __forceinline__ u16 f2bf(float f) {
    union { float f; u32 u; } v; v.f = f;
    u32 r = v.u + 0x7fffu + ((v.u >> 16) & 1u);   // RNE
    return (u16)(r >> 16);
}
__device__ __forceinline__ float bf2f(u16 u) {
    union { u32 u; float f; } v; v.u = ((u32)u) << 16; return v.f;
}
__device__ __forceinline__ float fsig(float x) {
    float t = __builtin_amdgcn_exp2f(-1.44269504f * x);
    return __builtin_amdgcn_rcpf(1.0f + t);
}
__device__ __forceinline__ float ftanh_(float x) {
    float xc = fminf(8.0f, fmaxf(-8.0f, x));
    float t = __builtin_amdgcn_exp2f(2.88539008f * xc);
    return (t - 1.0f) * __builtin_amdgcn_rcpf(t + 1.0f);
}
__device__ __forceinline__ void gl_lds16(const void* g, void* l) {
    __builtin_amdgcn_global_load_lds(
        (const __attribute__((address_space(1))) void*)g,
        (__attribute__((address_space(3))) void*)l, 16, 0, 0);
}

// ---------------- P1 (merged): W-fragment transform + embedding gather ----------------
// prep_w part: cid = nc*8 + np*4 + kq (0..255). Wave (np,kq) owns gates {2np,2np+1},
// K cols s = 4f+kq (f 0..19). Chunk layout: [f][n][lane][j8]; elem (l,j):
//   W[(4f+kq)*16 + (l>>5)*8 + j][(2np+n)*1024 + nc*32 + (l&31)]
__global__ void prep_all(const float* __restrict__ W, u16* __restrict__ Wf,
                         const int* __restrict__ tokens, const float* __restrict__ emb,
                         u16* __restrict__ X) {
    __shared__ u16 tile[64 * 72];
    int bid = blockIdx.x;
    int tid = threadIdx.x;
    if (bid < 1280) {
        int cid = bid / 5, fo = bid % 5;
        int kq  = cid & 3, np = (cid >> 2) & 1, nc = cid >> 3;
        int cc = tid & 31, n = (tid >> 5) & 1, r = tid >> 6;   // r 0..3
        int col = (np * 2 + n) * 1024 + nc * 32 + cc;
#pragma unroll
        for (int fl = 0; fl < 4; ++fl) {
            int k0 = (4 * (fo * 4 + fl) + kq) * 16;
#pragma unroll
            for (int rr = 0; rr < 4; ++rr) {
                int krow = rr * 4 + r;
                float v = W[(size_t)(k0 + krow) * 4096 + col];
                tile[(n * 32 + cc) * 72 + fl * 16 + krow] = f2bf(v);
            }
        }
        __syncthreads();
        int lane = tid & 63, wvv = tid >> 6;
#pragma unroll
        for (int pass = 0; pass < 2; ++pass) {
            int slot = wvv + pass * 4;
            int fl = slot >> 1, nn = slot & 1;
            v4i o = *(const v4i*)&tile[(nn * 32 + (lane & 31)) * 72 + fl * 16 + ((lane >> 5) << 3)];
            *(v4i*)(Wf + (size_t)cid * 20480 + (((fo * 4 + fl) * 2 + nn) << 9) + lane * 8) = o;
        }
    } else {
        int v   = (bid - 1280) * 256 + tid;           // < 983040
        int e8  = v & 31;
        int row = v >> 5;                             // t*256 + b
        int t = row >> 8, b = row & 255;
        int tok = tokens[b * T_ + t];
        const float* src = emb + (size_t)tok * E_ + e8 * 8;
        u16 o[8];
#pragma unroll
        for (int j = 0; j < 8; ++j) o[j] = f2bf(src[j]);
        *(v4i*)(X + (size_t)row * E_ + e8 * 8) = *(v4i*)o;
    }
}

// ---------------- main persistent LSTM kernel ----------------
// 256 blocks x 512 threads. Block (mchunk=bid&7, nc=bid>>3). Wave (np=wv>>2,
// kq=wv&3): gates {2np,2np+1} x K-quarter -> 2 MFMAs per A-frag read.
// Handshake: ONE flag per (mgroup, step), count 32, 64B-padded line, tid0-only
// poll + syncthreads (R4-proven; R5's all-wave polling caused LLC contention).
// x-part MFMAs for t+1 run post-flag to hide the handshake.
__global__ __launch_bounds__(512, 2) void lstm_main(
    const u16* __restrict__ Wf, const u16* __restrict__ X,
    const float* __restrict__ b_lstm, u16* __restrict__ hs,
    u32* __restrict__ bar) {

    __shared__ u16  hbuf[32 * LDH];           // 66,048 B
    __shared__ u16  xbuf[32 * LDX];           // 16,896 B
    __shared__ float gates[4 * 4 * 32 * 34];  // 69,632 B  [kq][gate][row][34]
    __shared__ float bias[128];               // 153,088 total

    const int tid   = threadIdx.x;
    const int lane  = tid & 63;
    const int wv    = tid >> 6;
    const int np    = wv >> 2;
    const int kq    = wv & 3;
    const int bid   = blockIdx.x;
    const int mchunk = bid & 7;
    const int nc    = bid >> 3;
    const int m0    = mchunk << 5;

    if (tid < 128) bias[tid] = b_lstm[(tid >> 5) * H_ + (nc << 5) + (tid & 31)];

    // ---- resident W fragments: [f 0..19][n 0..1], pinned ----
    v8s Wr[20][2];
    {
        const v4i* wsrc = (const v4i*)(Wf + (size_t)(nc * 8 + np * 4 + kq) * 20480);
#pragma unroll
        for (int f = 0; f < 20; ++f)
#pragma unroll
            for (int n = 0; n < 2; ++n)
                Wr[f][n] = __builtin_bit_cast(v8s, wsrc[(f * 2 + n) * 64 + lane]);
    }
#pragma unroll
    for (int f = 0; f < 20; ++f) {
        asm volatile("" : "+v"(Wr[f][0]));
        asm volatile("" : "+v"(Wr[f][1]));
    }

    // ---- stage X_0 ----
    {
        const v4i* xs = (const v4i*)(X + (size_t)m0 * E_);
#pragma unroll
        for (int i = 0; i < 2; ++i) {
            int idx = tid + i * 512;
            int r = idx >> 5, c8 = idx & 31;
            *(v4i*)&xbuf[r * LDX + c8 * 8] = xs[r * 32 + c8];
        }
    }
    __syncthreads();

    const u16* Ax = &xbuf[(lane & 31) * LDX + ((lane >> 5) << 3)];
    const u16* Ah = &hbuf[(lane & 31) * LDH + ((lane >> 5) << 3)];

    // ---- x-part MFMA for t=0 (f 0..3, both n-tiles) ----
    v16f acc0 = {0,0,0,0,0,0,0,0,0,0,0,0,0,0,0,0};
    v16f acc1 = {0,0,0,0,0,0,0,0,0,0,0,0,0,0,0,0};
#pragma unroll
    for (int f = 0; f < 4; ++f) {
        v8s a = *(const v8s*)(Ax + (4 * f + kq) * 16);
        acc0 = __builtin_amdgcn_mfma_f32_32x32x16_bf16(a, Wr[f][0], acc0, 0, 0, 0);
        acc1 = __builtin_amdgcn_mfma_f32_32x32x16_bf16(a, Wr[f][1], acc1, 0, 0, 0);
    }

    float cst[2] = {0.f, 0.f};
    const int cm  = tid >> 4;
    const int cn2 = (tid & 15) << 1;
    u32* hs32 = (u32*)hs;

    for (int t = 0; t < T_; ++t) {
        if (t > 0) {
            // ---- wait for h_{t-1}: tid0-only poll of padded flag ----
            if (tid == 0) {
                u32* p = &bar[((size_t)(mchunk * T_ + (t - 1))) << 4];
                while (__hip_atomic_load(p, __ATOMIC_RELAXED, __HIP_MEMORY_SCOPE_AGENT) < 32u)
                    __builtin_amdgcn_s_sleep(1);
            }
            __syncthreads();
            // ---- issue async h loads: wave wv -> rows [wv*4,+4), low then high half ----
            {
                const u16* srcb = hs + ((size_t)(t - 1) * B_ + m0) * H_;
                const int r0 = wv << 2;
#pragma unroll
                for (int i = 0; i < 4; ++i)
                    gl_lds16(srcb + (size_t)(r0 + i) * H_ + lane * 8,
                             &hbuf[(r0 + i) * LDH]);
#pragma unroll
                for (int i = 0; i < 4; ++i)
                    gl_lds16(srcb + (size_t)(r0 + i) * H_ + 512 + lane * 8,
                             &hbuf[(r0 + i) * LDH + 512]);
            }
            // ---- chunk A: h cols [0,512) (f 4..11) ----
            asm volatile("s_waitcnt vmcnt(4)\n\ts_barrier" ::: "memory");
#pragma unroll
            for (int f = 4; f < 12; ++f) {
                v8s a = *(const v8s*)(Ah + (4 * f + kq) * 16 - 256);
                acc0 = __builtin_amdgcn_mfma_f32_32x32x16_bf16(a, Wr[f][0], acc0, 0, 0, 0);
                acc1 = __builtin_amdgcn_mfma_f32_32x32x16_bf16(a, Wr[f][1], acc1, 0, 0, 0);
            }
            // ---- chunk B: h cols [512,1024) (f 12..19) ----
            asm volatile("s_waitcnt vmcnt(0)\n\ts_barrier" ::: "memory");
#pragma unroll
            for (int f = 12; f < 20; ++f) {
                v8s a = *(const v8s*)(Ah + (4 * f + kq) * 16 - 256);
                acc0 = __builtin_amdgcn_mfma_f32_32x32x16_bf16(a, Wr[f][0], acc0, 0, 0, 0);
                acc1 = __builtin_amdgcn_mfma_f32_32x32x16_bf16(a, Wr[f][1], acc1, 0, 0, 0);
            }
        }

        // ---- partials -> LDS: C/D col=lane&31, row=(reg&3)+8*(reg>>2)+4*(lane>>5) ----
        {
            int col = lane & 31, rq = (lane >> 5) << 2;
            float* g0 = &gates[(kq * 4 + np * 2 + 0) * 1088];
            float* g1 = &gates[(kq * 4 + np * 2 + 1) * 1088];
#pragma unroll
            for (int reg = 0; reg < 16; ++reg) {
                int row = (reg & 3) + ((reg >> 2) << 3) + rq;
                g0[row * 34 + col] = acc0[reg];
                g1[row * 34 + col] = acc1[reg];
            }
        }
        __syncthreads();                      // (1) gates ready; hbuf/xbuf reads done

        // ---- prefetch X_{t+1} into xbuf (overlaps cell transcendentals) ----
        if (t + 1 < T_) {
            const v4i* xs = (const v4i*)(X + ((size_t)(t + 1) * B_ + m0) * E_);
#pragma unroll
            for (int i = 0; i < 2; ++i) {
                int idx = tid + i * 512;
                int r = idx >> 5, c8 = idx & 31;
                *(v4i*)&xbuf[r * LDX + c8 * 8] = xs[r * 32 + c8];
            }
        }

        // ---- cell math: sum 4 K-partials, bias, activations ----
        u32 hpack = 0;
        {
            v2f zz[4];
#pragma unroll
            for (int gg = 0; gg < 4; ++gg) {
                v2f s0 = *(const v2f*)&gates[(0 * 4 + gg) * 1088 + cm * 34 + cn2];
                v2f s1 = *(const v2f*)&gates[(1 * 4 + gg) * 1088 + cm * 34 + cn2];
                v2f s2 = *(const v2f*)&gates[(2 * 4 + gg) * 1088 + cm * 34 + cn2];
                v2f s3 = *(const v2f*)&gates[(3 * 4 + gg) * 1088 + cm * 34 + cn2];
                zz[gg].x = (s0.x + s1.x) + (s2.x + s3.x);
                zz[gg].y = (s0.y + s1.y) + (s2.y + s3.y);
            }
#pragma unroll
            for (int q = 0; q < 2; ++q) {
                int n = cn2 + q;
                float ip = zz[0][q] + bias[n];
                float jp = zz[1][q] + bias[32 + n];
                float fp = zz[2][q] + bias[64 + n] + 1.0f;
                float op = zz[3][q] + bias[96 + n];
                float cc = fsig(fp) * cst[q] + fsig(ip) * ftanh_(jp);
                cst[q] = cc;
                hpack |= ((u32)f2bf(fsig(op) * ftanh_(cc))) << (16 * q);
            }
        }
        __hip_atomic_store(&hs32[((size_t)t * B_ + m0 + cm) * 512 + (nc << 4) + (tid & 15)],
                           hpack, __ATOMIC_RELAXED, __HIP_MEMORY_SCOPE_AGENT);

        if (t + 1 < T_) {
            // ---- release: drain own stores, block rendezvous, tid0 flag++ ----
            asm volatile("s_waitcnt vmcnt(0)" ::: "memory");
            __syncthreads();                  // (2)
            if (tid == 0)
                __hip_atomic_fetch_add(&bar[((size_t)(mchunk * T_ + t)) << 4], 1u,
                                       __ATOMIC_RELAXED, __HIP_MEMORY_SCOPE_AGENT);
            // ---- x-part MFMA for t+1 (hides the inter-block handshake) ----
#pragma unroll
            for (int reg = 0; reg < 16; ++reg) { acc0[reg] = 0.f; acc1[reg] = 0.f; }
#pragma unroll
            for (int f = 0; f < 4; ++f) {
                v8s a = *(const v8s*)(Ax + (4 * f + kq) * 16);
                acc0 = __builtin_amdgcn_mfma_f32_32x32x16_bf16(a, Wr[f][0], acc0, 0, 0, 0);
                acc1 = __builtin_amdgcn_mfma_f32_32x32x16_bf16(a, Wr[f][1], acc1, 0, 0, 0);
            }
        }
    }
}

// ---------------- P3: preds = hs @ U + b2 (64 rows/block; U staged once) ----------------
__global__ void proj_kernel(const u16* __restrict__ hs, const float* __restrict__ U,
                            const float* __restrict__ b2, float* __restrict__ out) {
    __shared__ float Ul[H_ * 5];
    int tid = threadIdx.x;
    for (int i = tid; i < H_ * 5; i += 256) Ul[i] = U[i];
    __syncthreads();
    int wv = tid >> 6, lane = tid & 63;
#pragma unroll 1
    for (int i = 0; i < 16; ++i) {
        int row = blockIdx.x * 64 + wv * 16 + i;   // t*256 + b, < 30720
        int t = row >> 8, b = row & 255;
        const v4i* hp = (const v4i*)(hs + (size_t)row * H_);
        float p[5] = {0.f, 0.f, 0.f, 0.f, 0.f};
#pragma unroll
        for (int half = 0; half < 2; ++half) {
            v4i hv = hp[lane * 2 + half];
            u16 us[8];
            *(v4i*)us = hv;
#pragma unroll
            for (int j = 0; j < 8; ++j) {
                float hf = bf2f(us[j]);
                int k = lane * 16 + half * 8 + j;
#pragma unroll
                for (int c = 0; c < 5; ++c) p[c] += hf * Ul[k * 5 + c];
            }
        }
#pragma unroll
        for (int c = 0; c < 5; ++c)
            for (int off = 32; off > 0; off >>= 1)
                p[c] += __shfl_down(p[c], off, 64);
        if (lane == 0) {
#pragma unroll
            for (int c = 0; c < 5; ++c)
                out[((size_t)b * T_ + t) * 5 + c] = p[c] + b2[c];
        }
    }
}

extern "C" void kernel_launch(void* const* d_in, const int* in_sizes, int n_in,
                              void* d_out, int out_size, void* d_ws, size_t ws_size,
                              hipStream_t stream) {
    const int*   tokens = (const int*)d_in[0];
    const float* emb    = (const float*)d_in[1];
    const float* W      = (const float*)d_in[2];
    const float* b_l    = (const float*)d_in[3];
    const float* U      = (const float*)d_in[4];
    const float* b2     = (const float*)d_in[5];
    float* out = (float*)d_out;

    char* ws = (char*)d_ws;
    u16* Wf  = (u16*)(ws + WS_WF);
    u16* X   = (u16*)(ws + WS_X);
    u16* hs  = (u16*)(ws + WS_HS);
    u32* bar = (u32*)(ws + WS_BAR);

    hipMemsetAsync(bar, 0, 8 * T_ * 16 * sizeof(u32), stream);
    prep_all<<<5120, 256, 0, stream>>>(W, Wf, tokens, emb, X);
    lstm_main<<<256, 512, 0, stream>>>(Wf, X, b_l, hs, bar);
    proj_kernel<<<480, 256, 0, stream>>>(hs, U, b2, out);
}